// Round 2
// baseline (1041.406 us; speedup 1.0000x reference)
//
#include <hip/hip_runtime.h>
#include <math.h>

#define NN   2048
#define BB   8
#define FF   64
#define HH   32
#define DIMM 34
#define CAP  256

// ---- workspace layout in 4-byte units ----
#define G_OFF      0                          // B*N*64 floats (g = [x,state])
#define DEM_OFF    (G_OFF + BB*NN*FF)         // B*N*2
#define W1T_OFF    (DEM_OFF + BB*NN*2)        // 2*N*64  (w1 transposed)
#define CNT_OFF    (W1T_OFF + 2*NN*FF)        // 4*N ints: ccntA, rcntA, ccntB, rcntB
#define NBRA_OFF   (CNT_OFF + 4*NN)           // N*CAP int  (col lists of A)
#define RNBRA_OFF  (NBRA_OFF + NN*CAP)        // N*CAP int  (row lists of A)
#define NBRB_OFF   (RNBRA_OFF + NN*CAP)       // N*CAP int
#define RNBRB_OFF  (NBRB_OFF + NN*CAP)        // N*CAP int
#define WAW2_OFF   (RNBRB_OFF + NN*CAP)       // N*CAP f32 (A ⊙ w2c[0], column-packed)
#define WAR_OFF    (WAW2_OFF + NN*CAP)        // A ⊙ wr
#define WAU_OFF    (WAR_OFF + NN*CAP)         // A ⊙ wu
#define WAC_OFF    (WAU_OFF + NN*CAP)         // A ⊙ wc
#define WBW2_OFF   (WAC_OFF + NN*CAP)         // Badj ⊙ w2c[1]
#define U_OFF      (WBW2_OFF + NN*CAP)        // B*N*32 (u)
#define RS_OFF     (U_OFF + BB*NN*HH)         // B*N*32 (r*state)

// ---------------- stage 1: x, g, demand ----------------
__global__ void k_pre(const float* __restrict__ in, const float* __restrict__ st,
                      const float* __restrict__ lininW, const float* __restrict__ lininB,
                      const float* __restrict__ convW, const float* __restrict__ convB,
                      float* __restrict__ g, float* __restrict__ dem) {
    int bn = blockIdx.x;        // b*N+n
    int f  = threadIdx.x;       // 0..63
    float in0 = in[bn * 2 + 0];
    float in1 = in[bn * 2 + 1];
    float gv;
    if (f < HH) gv = in0 * lininW[f] + in1 * lininW[HH + f] + lininB[f];
    else        gv = st[bn * HH + (f - HH)];
    g[bn * FF + f] = gv;
    float p0 = gv * convW[f * 2 + 0];
    float p1 = gv * convW[f * 2 + 1];
    for (int o = 32; o > 0; o >>= 1) { p0 += __shfl_down(p0, o); p1 += __shfl_down(p1, o); }
    if (f == 0) {
        dem[bn * 2 + 0] = tanhf(p0 + convB[0]) * 0.5f;
        dem[bn * 2 + 1] = tanhf(p1 + convB[1]) * 0.5f;
    }
}

// ---------------- transpose w1c[2][64][2048] -> w1T[2][2048][64] ----------------
__global__ void k_trans(const float* __restrict__ w1c, float* __restrict__ w1T) {
    int t = blockIdx.x * 256 + threadIdx.x;     // < 2*64*2048
    int a   = t >> 17;
    int rem = t & 131071;
    int f   = rem >> 11;
    int k   = rem & 2047;
    w1T[a * (NN * FF) + k * FF + f] = w1c[t];
}

// ---------------- build CSR-ish lists for both adjacencies ----------------
__global__ void k_fill(const float* __restrict__ A, const float* __restrict__ Badj,
                       const float* __restrict__ w2c,
                       const float* __restrict__ wr, const float* __restrict__ wu,
                       const float* __restrict__ wc,
                       int* __restrict__ cnt,   // [ccntA, rcntA, ccntB, rcntB]
                       int* __restrict__ nbrA, int* __restrict__ rnbrA,
                       int* __restrict__ nbrB, int* __restrict__ rnbrB,
                       float* __restrict__ wAw2, float* __restrict__ wAr,
                       float* __restrict__ wAu, float* __restrict__ wAc,
                       float* __restrict__ wBw2) {
    int t = blockIdx.x * 256 + threadIdx.x;
    const int NSQ = NN * NN;
    if (t < NSQ) {
        float a = A[t];
        if (a != 0.0f) {
            int n = t / NN, m = t % NN;
            int cj = atomicAdd(&cnt[m], 1);
            if (cj < CAP) {
                nbrA[m * CAP + cj] = n;
                wAw2[m * CAP + cj] = a * w2c[t];
                wAr [m * CAP + cj] = a * wr[t];
                wAu [m * CAP + cj] = a * wu[t];
                wAc [m * CAP + cj] = a * wc[t];
            }
            int rj = atomicAdd(&cnt[NN + n], 1);
            if (rj < CAP) rnbrA[n * CAP + rj] = m;
        }
    } else {
        int t2 = t - NSQ;
        float a = Badj[t2];
        if (a != 0.0f) {
            int n = t2 / NN, m = t2 % NN;
            int cj = atomicAdd(&cnt[2 * NN + m], 1);
            if (cj < CAP) {
                nbrB[m * CAP + cj] = n;
                wBw2[m * CAP + cj] = a * w2c[NSQ + t2];
            }
            int rj = atomicAdd(&cnt[3 * NN + n], 1);
            if (rj < CAP) rnbrB[n * CAP + rj] = m;
        }
    }
}

// ---------------- fused h-gather + masked softmax + weighted sum -> p ----------------
__global__ void k_attn(const float* __restrict__ g, const float* __restrict__ in,
                       const float* __restrict__ dem, const float* __restrict__ w1T,
                       const float* __restrict__ biasc, const int* __restrict__ cnt,
                       const int* __restrict__ nbrA, const float* __restrict__ wAw2,
                       const int* __restrict__ rnbrA,
                       const int* __restrict__ nbrB, const float* __restrict__ wBw2,
                       const int* __restrict__ rnbrB,
                       float* __restrict__ pOut) {
    int blk  = blockIdx.x;
    int comp = (blk >= BB * NN) ? 1 : 0;
    int bn   = comp ? blk - BB * NN : blk;
    int b = bn / NN, i = bn % NN;
    int lane = threadIdx.x;

    const int*   ccnt = comp ? (cnt + 2 * NN) : cnt;
    const int*   rcnt = comp ? (cnt + 3 * NN) : (cnt + NN);
    const int*   nbr  = comp ? nbrB : nbrA;
    const float* wv   = comp ? wBw2 : wAw2;
    const int*   rnbr = comp ? rnbrB : rnbrA;

    __shared__ float hs[FF];

    // phase 1: h[b,i,f] = sum over in-neighbors n of (adj*w2)[n,i] * g[b,n,f]
    int cc = ccnt[i]; if (cc > CAP) cc = CAP;
    const float* gb = g + (size_t)b * NN * FF;
    float acc = 0.0f;
    for (int j = 0; j < cc; ++j) {
        int n = nbr[i * CAP + j];
        acc += wv[i * CAP + j] * gb[n * FF + lane];
    }
    hs[lane] = acc;
    __syncthreads();

    // phase 2: neighbor-only scores + softmax + weighted sum of input column
    int rc = rcnt[i]; if (rc > CAP) rc = CAP;
    float bias = biasc[comp * NN + i];   // per-row constant (softmax-invariant, kept for exactness)
    float sj[4]; int kj[4];
    float lmax = -3.0e38f;
#pragma unroll
    for (int q = 0; q < 4; ++q) {
        int j = lane + q * 64;
        float s = -3.0e38f; int k = 0;
        if (j < rc) {
            k = rnbr[i * CAP + j];
            const float4* w4 = (const float4*)(w1T + ((size_t)comp * NN + k) * FF);
            s = bias;
#pragma unroll
            for (int f = 0; f < 16; ++f) {
                float4 w = w4[f];
                s += hs[4*f+0] * w.x + hs[4*f+1] * w.y + hs[4*f+2] * w.z + hs[4*f+3] * w.w;
            }
        }
        sj[q] = s; kj[q] = k;
        lmax = fmaxf(lmax, s);
    }
    for (int o = 32; o > 0; o >>= 1) lmax = fmaxf(lmax, __shfl_xor(lmax, o));
    float num = 0.0f, den = 0.0f;
    const float* inb = in + (size_t)b * NN * 2;
#pragma unroll
    for (int q = 0; q < 4; ++q) {
        int j = lane + q * 64;
        if (j < rc) {
            float e = expf(sj[q] - lmax);
            den += e;
            num += e * inb[kj[q] * 2 + comp];
        }
    }
    for (int o = 32; o > 0; o >>= 1) { num += __shfl_xor(num, o); den += __shfl_xor(den, o); }
    if (lane == 0) pOut[(size_t)bn * 2 + comp] = num / den + dem[bn * 2 + comp];
}

// ---------------- r,u gates ----------------
__global__ void k_ru(const float* __restrict__ pOut, const float* __restrict__ st,
                     const int* __restrict__ cnt, const int* __restrict__ nbrA,
                     const float* __restrict__ wAr, const float* __restrict__ wAu,
                     const float* __restrict__ br, const float* __restrict__ bu,
                     const float* __restrict__ linrW, const float* __restrict__ linrB,
                     const float* __restrict__ linuW, const float* __restrict__ linuB,
                     float* __restrict__ ubuf, float* __restrict__ rsbuf) {
    int bn = blockIdx.x;
    int b = bn / NN, i = bn % NN;
    int lane = threadIdx.x;
    __shared__ float Lr[DIMM], Lu[DIMM];
    int cc = cnt[i]; if (cc > CAP) cc = CAP;
    if (lane < DIMM) {
        float ar = 0.0f, au = 0.0f;
        for (int j = 0; j < cc; ++j) {
            int n = nbrA[i * CAP + j];
            float v = (lane < 2) ? pOut[((size_t)b * NN + n) * 2 + lane]
                                 : st[((size_t)b * NN + n) * HH + (lane - 2)];
            float wr_ = wAr[i * CAP + j];
            float wu_ = wAu[i * CAP + j];
            ar += wr_ * v;
            au += wu_ * v;
        }
        Lr[lane] = ar + br[lane];
        Lu[lane] = au + bu[lane];
    }
    __syncthreads();
    if (lane < HH) {
        float s = linrB[lane];
        for (int d = 0; d < DIMM; ++d) s += Lr[d] * linrW[d * HH + lane];
        float r = 1.0f / (1.0f + expf(-s));
        rsbuf[(size_t)bn * HH + lane] = r * st[(size_t)bn * HH + lane];
    } else {
        int h = lane - HH;
        float s = linuB[h];
        for (int d = 0; d < DIMM; ++d) s += Lu[d] * linuW[d * HH + h];
        ubuf[(size_t)bn * HH + h] = 1.0f / (1.0f + expf(-s));
    }
}

// ---------------- c and final H ----------------
__global__ void k_c(const float* __restrict__ g, const float* __restrict__ rsbuf,
                    const float* __restrict__ ubuf, const float* __restrict__ st,
                    const int* __restrict__ cnt, const int* __restrict__ nbrA,
                    const float* __restrict__ wAc, const float* __restrict__ bc,
                    const float* __restrict__ lincW, const float* __restrict__ lincB,
                    float* __restrict__ Hout) {
    int bn = blockIdx.x;
    int b = bn / NN, i = bn % NN;
    int lane = threadIdx.x;
    __shared__ float Lc[FF];
    int cc = cnt[i]; if (cc > CAP) cc = CAP;
    float acc = 0.0f;
    for (int j = 0; j < cc; ++j) {
        int n = nbrA[i * CAP + j];
        float v = (lane < HH) ? g[((size_t)b * NN + n) * FF + lane]          // x part
                              : rsbuf[((size_t)b * NN + n) * HH + (lane - HH)]; // r*state part
        acc += wAc[i * CAP + j] * v;
    }
    Lc[lane] = acc + bc[lane];
    __syncthreads();
    if (lane < HH) {
        float s = lincB[lane];
        for (int f = 0; f < FF; ++f) s += Lc[f] * lincW[f * HH + lane];
        float c = tanhf(s);
        float u = ubuf[(size_t)bn * HH + lane];
        float stv = st[(size_t)bn * HH + lane];
        Hout[(size_t)bn * HH + lane] = u * stv + (1.0f - u) * c;
    }
}

extern "C" void kernel_launch(void* const* d_in, const int* in_sizes, int n_in,
                              void* d_out, int out_size, void* d_ws, size_t ws_size,
                              hipStream_t stream) {
    const float* input  = (const float*)d_in[0];
    const float* state  = (const float*)d_in[1];
    const float* A      = (const float*)d_in[2];
    const float* Badj   = (const float*)d_in[3];
    const float* w1c    = (const float*)d_in[4];
    const float* w2c    = (const float*)d_in[5];
    const float* biasc  = (const float*)d_in[6];
    const float* convW  = (const float*)d_in[7];
    const float* convb  = (const float*)d_in[8];
    const float* lininW = (const float*)d_in[9];
    const float* lininB = (const float*)d_in[10];
    const float* wr     = (const float*)d_in[11];
    const float* br     = (const float*)d_in[12];
    const float* linrW  = (const float*)d_in[13];
    const float* linrB  = (const float*)d_in[14];
    const float* wu     = (const float*)d_in[15];
    const float* bu     = (const float*)d_in[16];
    const float* linuW  = (const float*)d_in[17];
    const float* linuB  = (const float*)d_in[18];
    const float* wc     = (const float*)d_in[19];
    const float* bc     = (const float*)d_in[20];
    const float* lincW  = (const float*)d_in[21];
    const float* lincB  = (const float*)d_in[22];

    float* ws   = (float*)d_ws;
    float* g    = ws + G_OFF;
    float* dem  = ws + DEM_OFF;
    float* w1T  = ws + W1T_OFF;
    int*   cnt  = (int*)(ws + CNT_OFF);
    int*   nbrA = (int*)(ws + NBRA_OFF);
    int*   rnbrA= (int*)(ws + RNBRA_OFF);
    int*   nbrB = (int*)(ws + NBRB_OFF);
    int*   rnbrB= (int*)(ws + RNBRB_OFF);
    float* wAw2 = ws + WAW2_OFF;
    float* wAr  = ws + WAR_OFF;
    float* wAu  = ws + WAU_OFF;
    float* wAc  = ws + WAC_OFF;
    float* wBw2 = ws + WBW2_OFF;
    float* ubuf = ws + U_OFF;
    float* rsbuf= ws + RS_OFF;

    float* pOut = (float*)d_out;                    // [B,N,2]
    float* Hout = (float*)d_out + BB * NN * 2;      // [B,N,32]

    hipMemsetAsync(cnt, 0, 4 * NN * sizeof(int), stream);

    k_pre<<<BB * NN, 64, 0, stream>>>(input, state, lininW, lininB, convW, convb, g, dem);
    k_trans<<<(2 * NN * FF) / 256, 256, 0, stream>>>(w1c, w1T);
    k_fill<<<(2 * NN * NN) / 256, 256, 0, stream>>>(A, Badj, w2c, wr, wu, wc, cnt,
                                                    nbrA, rnbrA, nbrB, rnbrB,
                                                    wAw2, wAr, wAu, wAc, wBw2);
    k_attn<<<2 * BB * NN, 64, 0, stream>>>(g, input, dem, w1T, biasc, cnt,
                                           nbrA, wAw2, rnbrA, nbrB, wBw2, rnbrB, pOut);
    k_ru<<<BB * NN, 64, 0, stream>>>(pOut, state, cnt, nbrA, wAr, wAu, br, bu,
                                     linrW, linrB, linuW, linuB, ubuf, rsbuf);
    k_c<<<BB * NN, 64, 0, stream>>>(g, rsbuf, ubuf, state, cnt, nbrA, wAc, bc,
                                    lincW, lincB, Hout);
}

// Round 6
// 668.434 us; speedup vs baseline: 1.5580x; 1.5580x over previous
//
#include <hip/hip_runtime.h>
#include <math.h>

#define NN   2048
#define BB   8
#define FF   64
#define HH   32
#define DIMM 34
#define CAP  256

// ---- workspace layout in 4-byte units ----
#define G_OFF      0                          // B*N*64 floats (g = [x,state])
#define DEM_OFF    (G_OFF + BB*NN*FF)         // B*N*2
#define W1T_OFF    (DEM_OFF + BB*NN*2)        // 2*N*64  (w1 transposed)
#define CNT_OFF    (W1T_OFF + 2*NN*FF)        // 4*N ints: ccntA, rcntA, ccntB, rcntB
#define NBRA_OFF   (CNT_OFF + 4*NN)           // N*CAP int  (col lists of A)
#define RNBRA_OFF  (NBRA_OFF + NN*CAP)        // N*CAP int  (row lists of A, sorted)
#define NBRB_OFF   (RNBRA_OFF + NN*CAP)       // N*CAP int
#define RNBRB_OFF  (NBRB_OFF + NN*CAP)        // N*CAP int
#define WAW2_OFF   (RNBRB_OFF + NN*CAP)       // N*CAP f32 (A ⊙ w2c[0], column-packed)
#define WAR_OFF    (WAW2_OFF + NN*CAP)        // A ⊙ wr
#define WAU_OFF    (WAR_OFF + NN*CAP)         // A ⊙ wu
#define WAC_OFF    (WAU_OFF + NN*CAP)         // A ⊙ wc
#define WBW2_OFF   (WAC_OFF + NN*CAP)         // Badj ⊙ w2c[1]
#define U_OFF      (WBW2_OFF + NN*CAP)        // B*N*32 (u)
#define RS_OFF     (U_OFF + BB*NN*HH)         // B*N*32 (r*state)

// ---------------- stage 1: x, g, demand ----------------
__global__ void k_pre(const float* __restrict__ in, const float* __restrict__ st,
                      const float* __restrict__ lininW, const float* __restrict__ lininB,
                      const float* __restrict__ convW, const float* __restrict__ convB,
                      float* __restrict__ g, float* __restrict__ dem) {
    int bn = blockIdx.x;        // b*N+n
    int f  = threadIdx.x;       // 0..63
    float in0 = in[bn * 2 + 0];
    float in1 = in[bn * 2 + 1];
    float gv;
    if (f < HH) gv = in0 * lininW[f] + in1 * lininW[HH + f] + lininB[f];
    else        gv = st[bn * HH + (f - HH)];
    g[bn * FF + f] = gv;
    float p0 = gv * convW[f * 2 + 0];
    float p1 = gv * convW[f * 2 + 1];
    for (int o = 32; o > 0; o >>= 1) { p0 += __shfl_down(p0, o); p1 += __shfl_down(p1, o); }
    if (f == 0) {
        dem[bn * 2 + 0] = tanhf(p0 + convB[0]) * 0.5f;
        dem[bn * 2 + 1] = tanhf(p1 + convB[1]) * 0.5f;
    }
}

// ---------------- transpose w1c[2][64][2048] -> w1T[2][2048][64] ----------------
__global__ void k_trans(const float* __restrict__ w1c, float* __restrict__ w1T) {
    int t = blockIdx.x * 256 + threadIdx.x;     // < 2*64*2048
    int a   = t >> 17;
    int rem = t & 131071;
    int f   = rem >> 11;
    int k   = rem & 2047;
    w1T[a * (NN * FF) + k * FF + f] = w1c[t];
}

// ---------------- build lists: one wave per adjacency row ----------------
// Row lists: deterministic (wave prefix scan, sorted by column). Column lists:
// one atomic per nnz; weight loads are independent of the atomic result.
__global__ void k_fill(const float* __restrict__ A, const float* __restrict__ Badj,
                       const float* __restrict__ w2c,
                       const float* __restrict__ wr, const float* __restrict__ wu,
                       const float* __restrict__ wc,
                       int* __restrict__ cnt,   // [ccntA, rcntA, ccntB, rcntB]
                       int* __restrict__ nbrA, int* __restrict__ rnbrA,
                       int* __restrict__ nbrB, int* __restrict__ rnbrB,
                       float* __restrict__ wAw2, float* __restrict__ wAr,
                       float* __restrict__ wAu, float* __restrict__ wAc,
                       float* __restrict__ wBw2) {
    int gw   = blockIdx.x * 4 + (threadIdx.x >> 6);   // global wave id, 0..2*NN-1
    int lane = threadIdx.x & 63;
    int comp = (gw >= NN) ? 1 : 0;
    int n    = comp ? gw - NN : gw;
    const float* row = (comp ? Badj : A) + (size_t)n * NN;

    // each lane owns 32 contiguous elements [lane*32, lane*32+32)
    const float4* r4 = (const float4*)row + lane * 8;
    unsigned int msk = 0;
#pragma unroll
    for (int q = 0; q < 8; ++q) {
        float4 v = r4[q];
        msk |= ((unsigned)(v.x != 0.0f)) << (q * 4 + 0);
        msk |= ((unsigned)(v.y != 0.0f)) << (q * 4 + 1);
        msk |= ((unsigned)(v.z != 0.0f)) << (q * 4 + 2);
        msk |= ((unsigned)(v.w != 0.0f)) << (q * 4 + 3);
    }
    int c    = __popc(msk);
    int incl = c;
#pragma unroll
    for (int o = 1; o < 64; o <<= 1) {
        int tv = __shfl_up(incl, o);
        if (lane >= o) incl += tv;
    }
    int slot  = incl - c;                 // exclusive prefix
    int total = __shfl(incl, 63);
    if (lane == 0) cnt[(comp ? 3 * NN : NN) + n] = total;   // row count

    int* rnbr   = comp ? rnbrB : rnbrA;
    int* nbr    = comp ? nbrB  : nbrA;
    int  colbase= comp ? 2 * NN : 0;
    unsigned int mm = msk;
    while (mm) {
        int p = __ffs(mm) - 1; mm &= mm - 1;
        int m = lane * 32 + p;
        if (slot < CAP) rnbr[n * CAP + slot] = m;
        slot++;
        int cj = atomicAdd(&cnt[colbase + m], 1);
        if (cj < CAP) {
            size_t tI = (size_t)n * NN + m;     // adjacency value is exactly 1.0 here
            nbr[m * CAP + cj] = n;
            if (!comp) {
                wAw2[m * CAP + cj] = w2c[tI];
                wAr [m * CAP + cj] = wr[tI];
                wAu [m * CAP + cj] = wu[tI];
                wAc [m * CAP + cj] = wc[tI];
            } else {
                wBw2[m * CAP + cj] = w2c[(size_t)NN * NN + tI];
            }
        }
    }
}

// ---------------- fused h-gather + masked softmax + p, all 8 batches/block ----------------
__global__ void k_attn(const float* __restrict__ g, const float* __restrict__ in,
                       const float* __restrict__ dem, const float* __restrict__ w1T,
                       const float* __restrict__ biasc, const int* __restrict__ cnt,
                       const int* __restrict__ nbrA, const float* __restrict__ wAw2,
                       const int* __restrict__ rnbrA,
                       const int* __restrict__ nbrB, const float* __restrict__ wBw2,
                       const int* __restrict__ rnbrB,
                       float* __restrict__ pOut) {
    int blk  = blockIdx.x;                   // 0..2*NN-1
    int comp = (blk >= NN) ? 1 : 0;
    int i    = comp ? blk - NN : blk;
    int t    = threadIdx.x;                  // 0..255

    const int*   ccnt = cnt + (comp ? 2 * NN : 0);
    const int*   rcnt = cnt + (comp ? 3 * NN : NN);
    const int*   nbr  = comp ? nbrB : nbrA;
    const float* wv   = comp ? wBw2 : wAw2;
    const int*   rnbr = comp ? rnbrB : rnbrA;

    __shared__ float hs[8][68];              // 16B-aligned rows, conflict-free

    // phase 1: h[b][f] for all 8 b; thread = (f = t&63, b in {t>>6, t>>6+4})
    int cc = ccnt[i]; if (cc > CAP) cc = CAP;
    int f  = t & 63;
    int b0 = t >> 6, b1 = b0 + 4;
    const float* g0 = g + (size_t)b0 * NN * FF + f;
    const float* g1 = g + (size_t)b1 * NN * FF + f;
    float a0 = 0.0f, a1 = 0.0f;
    for (int j = 0; j < cc; ++j) {
        int   n = nbr[i * CAP + j];          // uniform -> scalar load
        float w = wv[i * CAP + j];
        a0 += w * g0[n * FF];
        a1 += w * g1[n * FF];
    }
    hs[b0][f] = a0;
    hs[b1][f] = a1;
    __syncthreads();

    // phase 2: neighbor-only scores + softmax + weighted input sum
    // lane mapping: wave w handles b = 2w + (lane>>5); s = lane&31 slot
    int rc = rcnt[i]; if (rc > CAP) rc = CAP;
    int wvx  = t >> 6;
    int lane = t & 63;
    int b    = 2 * wvx + (lane >> 5);
    int s    = lane & 31;
    float bias = biasc[comp * NN + i];
    int rounds = (rc + 31) >> 5;             // <= 8
    float sc[8]; int nn8[8];
    float lmax = -3.0e38f;
#pragma unroll
    for (int r = 0; r < 8; ++r) {
        float svv = -3.0e38f; int n = 0;
        if (r < rounds) {
            int k = r * 32 + s;
            if (k < rc) {
                n = rnbr[i * CAP + k];
                const float4* w4 = (const float4*)(w1T + ((size_t)comp * NN + n) * FF);
                float acc = bias;
#pragma unroll
                for (int q = 0; q < 16; ++q) {
                    float4 w = w4[q];
                    acc += hs[b][4*q+0] * w.x + hs[b][4*q+1] * w.y
                         + hs[b][4*q+2] * w.z + hs[b][4*q+3] * w.w;
                }
                svv = acc;
            }
        }
        sc[r] = svv; nn8[r] = n;
        lmax = fmaxf(lmax, svv);
    }
#pragma unroll
    for (int o = 16; o > 0; o >>= 1) lmax = fmaxf(lmax, __shfl_xor(lmax, o));
    float num = 0.0f, den = 0.0f;
#pragma unroll
    for (int r = 0; r < 8; ++r) {
        if (r < rounds) {
            int k = r * 32 + s;
            if (k < rc) {
                float e = expf(sc[r] - lmax);
                den += e;
                num += e * in[((size_t)b * NN + nn8[r]) * 2 + comp];
            }
        }
    }
#pragma unroll
    for (int o = 16; o > 0; o >>= 1) { num += __shfl_xor(num, o); den += __shfl_xor(den, o); }
    if (s == 0) {
        size_t bn = (size_t)b * NN + i;
        pOut[bn * 2 + comp] = num / den + dem[bn * 2 + comp];
    }
}

// ---------------- r,u gates, all 8 batches/block ----------------
__global__ void k_ru(const float* __restrict__ pOut, const float* __restrict__ st,
                     const int* __restrict__ cnt, const int* __restrict__ nbrA,
                     const float* __restrict__ wAr, const float* __restrict__ wAu,
                     const float* __restrict__ br, const float* __restrict__ bu,
                     const float* __restrict__ linrW, const float* __restrict__ linrB,
                     const float* __restrict__ linuW, const float* __restrict__ linuB,
                     float* __restrict__ ubuf, float* __restrict__ rsbuf) {
    int i = blockIdx.x;
    int t = threadIdx.x;                 // 256
    int b = t >> 5, d = t & 31;          // d = state dim; fru dim = d+2
    __shared__ float Lr[8][36], Lu[8][36];
    int cc = cnt[i]; if (cc > CAP) cc = CAP;
    bool dop = (d < 2);
    float ar = 0.0f, au = 0.0f, arp = 0.0f, aup = 0.0f;
    for (int j = 0; j < cc; ++j) {
        int   n   = nbrA[i * CAP + j];   // uniform
        float wr_ = wAr[i * CAP + j];
        float wu_ = wAu[i * CAP + j];
        float v = st[((size_t)b * NN + n) * HH + d];
        ar += wr_ * v;  au += wu_ * v;
        if (dop) {
            float vp = pOut[((size_t)b * NN + n) * 2 + d];
            arp += wr_ * vp;  aup += wu_ * vp;
        }
    }
    Lr[b][d + 2] = ar + br[d + 2];
    Lu[b][d + 2] = au + bu[d + 2];
    if (dop) { Lr[b][d] = arp + br[d]; Lu[b][d] = aup + bu[d]; }
    __syncthreads();
    float sr = linrB[d], su = linuB[d];
#pragma unroll
    for (int q = 0; q < DIMM; ++q) {
        sr += Lr[b][q] * linrW[q * HH + d];
        su += Lu[b][q] * linuW[q * HH + d];
    }
    float r = 1.0f / (1.0f + expf(-sr));
    float u = 1.0f / (1.0f + expf(-su));
    size_t bn = (size_t)b * NN + i;
    rsbuf[bn * HH + d] = r * st[bn * HH + d];
    ubuf [bn * HH + d] = u;
}

// ---------------- c and final H, all 8 batches/block ----------------
__global__ void k_c(const float* __restrict__ g, const float* __restrict__ rsbuf,
                    const float* __restrict__ ubuf, const float* __restrict__ st,
                    const int* __restrict__ cnt, const int* __restrict__ nbrA,
                    const float* __restrict__ wAc, const float* __restrict__ bc,
                    const float* __restrict__ lincW, const float* __restrict__ lincB,
                    float* __restrict__ Hout) {
    int i = blockIdx.x;
    int t = threadIdx.x;                 // 256
    int b = t >> 5, d = t & 31;
    __shared__ float Lc[8][68];
    int cc = cnt[i]; if (cc > CAP) cc = CAP;
    float a0 = 0.0f, a1 = 0.0f;
    for (int j = 0; j < cc; ++j) {
        int   n = nbrA[i * CAP + j];     // uniform
        float w = wAc[i * CAP + j];
        a0 += w * g[((size_t)b * NN + n) * FF + d];          // x part (g[...][0..31])
        a1 += w * rsbuf[((size_t)b * NN + n) * HH + d];      // r*state part
    }
    Lc[b][d]      = a0 + bc[d];
    Lc[b][d + 32] = a1 + bc[d + 32];
    __syncthreads();
    float sacc = lincB[d];
#pragma unroll
    for (int q = 0; q < FF; ++q) sacc += Lc[b][q] * lincW[q * HH + d];
    float cv = tanhf(sacc);
    size_t bn = (size_t)b * NN + i;
    float u  = ubuf[bn * HH + d];
    float sv = st[bn * HH + d];
    Hout[bn * HH + d] = u * sv + (1.0f - u) * cv;
}

extern "C" void kernel_launch(void* const* d_in, const int* in_sizes, int n_in,
                              void* d_out, int out_size, void* d_ws, size_t ws_size,
                              hipStream_t stream) {
    const float* input  = (const float*)d_in[0];
    const float* state  = (const float*)d_in[1];
    const float* A      = (const float*)d_in[2];
    const float* Badj   = (const float*)d_in[3];
    const float* w1c    = (const float*)d_in[4];
    const float* w2c    = (const float*)d_in[5];
    const float* biasc  = (const float*)d_in[6];
    const float* convW  = (const float*)d_in[7];
    const float* convb  = (const float*)d_in[8];
    const float* lininW = (const float*)d_in[9];
    const float* lininB = (const float*)d_in[10];
    const float* wr     = (const float*)d_in[11];
    const float* br     = (const float*)d_in[12];
    const float* linrW  = (const float*)d_in[13];
    const float* linrB  = (const float*)d_in[14];
    const float* wu     = (const float*)d_in[15];
    const float* bu     = (const float*)d_in[16];
    const float* linuW  = (const float*)d_in[17];
    const float* linuB  = (const float*)d_in[18];
    const float* wc     = (const float*)d_in[19];
    const float* bc     = (const float*)d_in[20];
    const float* lincW  = (const float*)d_in[21];
    const float* lincB  = (const float*)d_in[22];

    float* ws   = (float*)d_ws;
    float* g    = ws + G_OFF;
    float* dem  = ws + DEM_OFF;
    float* w1T  = ws + W1T_OFF;
    int*   cnt  = (int*)(ws + CNT_OFF);
    int*   nbrA = (int*)(ws + NBRA_OFF);
    int*   rnbrA= (int*)(ws + RNBRA_OFF);
    int*   nbrB = (int*)(ws + NBRB_OFF);
    int*   rnbrB= (int*)(ws + RNBRB_OFF);
    float* wAw2 = ws + WAW2_OFF;
    float* wAr  = ws + WAR_OFF;
    float* wAu  = ws + WAU_OFF;
    float* wAc  = ws + WAC_OFF;
    float* wBw2 = ws + WBW2_OFF;
    float* ubuf = ws + U_OFF;
    float* rsbuf= ws + RS_OFF;

    float* pOut = (float*)d_out;                    // [B,N,2]
    float* Hout = (float*)d_out + BB * NN * 2;      // [B,N,32]

    hipMemsetAsync(cnt, 0, 4 * NN * sizeof(int), stream);

    k_pre<<<BB * NN, 64, 0, stream>>>(input, state, lininW, lininB, convW, convb, g, dem);
    k_trans<<<(2 * NN * FF) / 256, 256, 0, stream>>>(w1c, w1T);
    k_fill<<<(2 * NN) / 4, 256, 0, stream>>>(A, Badj, w2c, wr, wu, wc, cnt,
                                             nbrA, rnbrA, nbrB, rnbrB,
                                             wAw2, wAr, wAu, wAc, wBw2);
    k_attn<<<2 * NN, 256, 0, stream>>>(g, input, dem, w1T, biasc, cnt,
                                       nbrA, wAw2, rnbrA, nbrB, wBw2, rnbrB, pOut);
    k_ru<<<NN, 256, 0, stream>>>(pOut, state, cnt, nbrA, wAr, wAu, br, bu,
                                 linrW, linrB, linuW, linuB, ubuf, rsbuf);
    k_c<<<NN, 256, 0, stream>>>(g, rsbuf, ubuf, state, cnt, nbrA, wAc, bc,
                                lincW, lincB, Hout);
}

// Round 9
// 483.544 us; speedup vs baseline: 2.1537x; 1.3824x over previous
//
#include <hip/hip_runtime.h>
#include <math.h>

#define NN   2048
#define BB   8
#define FF   64
#define HH   32
#define DIMM 34
#define CAP  256

// ---- workspace layout in 4-byte units ----
#define G_OFF      0                          // B*N*64 floats (g = [x,state])
#define DEM_OFF    (G_OFF + BB*NN*FF)         // B*N*2
#define W1T_OFF    (DEM_OFF + BB*NN*2)        // 2*N*64  (w1 transposed)
#define CNT_OFF    (W1T_OFF + 2*NN*FF)        // 4*N ints: ccntA, rcntA, ccntB, rcntB
#define NBRA_OFF   (CNT_OFF + 4*NN)           // N*CAP int  (col lists of A)
#define RNBRA_OFF  (NBRA_OFF + NN*CAP)        // N*CAP int  (row lists of A, sorted)
#define NBRB_OFF   (RNBRA_OFF + NN*CAP)       // N*CAP int
#define RNBRB_OFF  (NBRB_OFF + NN*CAP)        // N*CAP int
#define WAW2_OFF   (RNBRB_OFF + NN*CAP)       // N*CAP f32 (A ⊙ w2c[0], column-packed)
#define WAR_OFF    (WAW2_OFF + NN*CAP)        // A ⊙ wr
#define WAU_OFF    (WAR_OFF + NN*CAP)        // A ⊙ wu
#define WAC_OFF    (WAU_OFF + NN*CAP)        // A ⊙ wc
#define WBW2_OFF   (WAC_OFF + NN*CAP)        // Badj ⊙ w2c[1]
#define U_OFF      (WBW2_OFF + NN*CAP)       // B*N*32 (u)
#define RS_OFF     (U_OFF + BB*NN*HH)        // B*N*32 (r*state)

// ---------------- stage 1: x, g, demand ----------------
__global__ void k_pre(const float* __restrict__ in, const float* __restrict__ st,
                      const float* __restrict__ lininW, const float* __restrict__ lininB,
                      const float* __restrict__ convW, const float* __restrict__ convB,
                      float* __restrict__ g, float* __restrict__ dem) {
    int bn = blockIdx.x;        // b*N+n
    int f  = threadIdx.x;       // 0..63
    float in0 = in[bn * 2 + 0];
    float in1 = in[bn * 2 + 1];
    float gv;
    if (f < HH) gv = in0 * lininW[f] + in1 * lininW[HH + f] + lininB[f];
    else        gv = st[bn * HH + (f - HH)];
    g[bn * FF + f] = gv;
    float p0 = gv * convW[f * 2 + 0];
    float p1 = gv * convW[f * 2 + 1];
    for (int o = 32; o > 0; o >>= 1) { p0 += __shfl_down(p0, o); p1 += __shfl_down(p1, o); }
    if (f == 0) {
        dem[bn * 2 + 0] = tanhf(p0 + convB[0]) * 0.5f;
        dem[bn * 2 + 1] = tanhf(p1 + convB[1]) * 0.5f;
    }
}

// ---------------- transpose w1c[2][64][2048] -> w1T[2][2048][64] ----------------
__global__ void k_trans(const float* __restrict__ w1c, float* __restrict__ w1T) {
    int t = blockIdx.x * 256 + threadIdx.x;     // < 2*64*2048
    int a   = t >> 17;
    int rem = t & 131071;
    int f   = rem >> 11;
    int k   = rem & 2047;
    w1T[a * (NN * FF) + k * FF + f] = w1c[t];
}

// ---------------- build lists: one wave per adjacency row ----------------
__global__ void k_fill(const float* __restrict__ A, const float* __restrict__ Badj,
                       const float* __restrict__ w2c,
                       const float* __restrict__ wr, const float* __restrict__ wu,
                       const float* __restrict__ wc,
                       int* __restrict__ cnt,   // [ccntA, rcntA, ccntB, rcntB]
                       int* __restrict__ nbrA, int* __restrict__ rnbrA,
                       int* __restrict__ nbrB, int* __restrict__ rnbrB,
                       float* __restrict__ wAw2, float* __restrict__ wAr,
                       float* __restrict__ wAu, float* __restrict__ wAc,
                       float* __restrict__ wBw2) {
    int gw   = blockIdx.x * 4 + (threadIdx.x >> 6);   // global wave id, 0..2*NN-1
    int lane = threadIdx.x & 63;
    int comp = (gw >= NN) ? 1 : 0;
    int n    = comp ? gw - NN : gw;
    const float* row = (comp ? Badj : A) + (size_t)n * NN;

    const float4* r4 = (const float4*)row + lane * 8;
    unsigned int msk = 0;
#pragma unroll
    for (int q = 0; q < 8; ++q) {
        float4 v = r4[q];
        msk |= ((unsigned)(v.x != 0.0f)) << (q * 4 + 0);
        msk |= ((unsigned)(v.y != 0.0f)) << (q * 4 + 1);
        msk |= ((unsigned)(v.z != 0.0f)) << (q * 4 + 2);
        msk |= ((unsigned)(v.w != 0.0f)) << (q * 4 + 3);
    }
    int c    = __popc(msk);
    int incl = c;
#pragma unroll
    for (int o = 1; o < 64; o <<= 1) {
        int tv = __shfl_up(incl, o);
        if (lane >= o) incl += tv;
    }
    int slot  = incl - c;
    int total = __shfl(incl, 63);
    if (lane == 0) cnt[(comp ? 3 * NN : NN) + n] = total;

    int* rnbr   = comp ? rnbrB : rnbrA;
    int* nbr    = comp ? nbrB  : nbrA;
    int  colbase= comp ? 2 * NN : 0;
    unsigned int mm = msk;
    while (mm) {
        int p = __ffs(mm) - 1; mm &= mm - 1;
        int m = lane * 32 + p;
        if (slot < CAP) rnbr[n * CAP + slot] = m;
        slot++;
        int cj = atomicAdd(&cnt[colbase + m], 1);
        if (cj < CAP) {
            size_t tI = (size_t)n * NN + m;
            nbr[m * CAP + cj] = n;
            if (!comp) {
                wAw2[m * CAP + cj] = w2c[tI];
                wAr [m * CAP + cj] = wr[tI];
                wAu [m * CAP + cj] = wu[tI];
                wAc [m * CAP + cj] = wc[tI];
            } else {
                wBw2[m * CAP + cj] = w2c[(size_t)NN * NN + tI];
            }
        }
    }
}

// ---------------- fused h-gather + masked softmax + p ----------------
// 512 threads. Phase 1: 4-way j-split, float4 gathers, unroll-4.
// Phase 2: 1 batch per wave, 64 softmax slots/round.
__global__ void __launch_bounds__(512)
k_attn(const float* __restrict__ g, const float* __restrict__ in,
       const float* __restrict__ dem, const float* __restrict__ w1T,
       const float* __restrict__ biasc, const int* __restrict__ cnt,
       const int* __restrict__ nbrA, const float* __restrict__ wAw2,
       const int* __restrict__ rnbrA,
       const int* __restrict__ nbrB, const float* __restrict__ wBw2,
       const int* __restrict__ rnbrB,
       float* __restrict__ pOut) {
    int blk  = blockIdx.x;                   // 0..2*NN-1
    int comp = (blk >= NN) ? 1 : 0;
    int i    = comp ? blk - NN : blk;
    int t    = threadIdx.x;                  // 0..511

    const int*   ccnt = cnt + (comp ? 2 * NN : 0);
    const int*   rcnt = cnt + (comp ? 3 * NN : NN);
    const int*   nbr  = comp ? nbrB : nbrA;
    const float* wv   = comp ? wBw2 : wAw2;
    const int*   rnbr = comp ? rnbrB : rnbrA;

    __shared__ float4 hsPart[4][8][16];      // 8 KB partials
    __shared__ float  hs[8][68];             // combined h, broadcast reads

    // ---- phase 1: h[b][f] ----
    int cc = ccnt[i]; if (cc > CAP) cc = CAP;
    {
        int f4 = t & 15;                     // float4 chunk of the 64-f row
        int b  = (t >> 4) & 7;
        int q  = t >> 7;                     // wave-uniform quarter
        int qlen = (cc + 3) >> 2;
        int jb = q * qlen;
        int je = jb + qlen; if (je > cc) je = cc;
        const float4* gb4 = (const float4*)g + (size_t)b * NN * 16 + f4;
        float4 acc = make_float4(0.f, 0.f, 0.f, 0.f);
        int j = jb;
        for (; j + 4 <= je; j += 4) {
            int   n0 = nbr[i * CAP + j + 0], n1 = nbr[i * CAP + j + 1];
            int   n2 = nbr[i * CAP + j + 2], n3 = nbr[i * CAP + j + 3];
            float w0 = wv[i * CAP + j + 0], w1 = wv[i * CAP + j + 1];
            float w2 = wv[i * CAP + j + 2], w3 = wv[i * CAP + j + 3];
            float4 x0 = gb4[n0 * 16], x1 = gb4[n1 * 16];
            float4 x2 = gb4[n2 * 16], x3 = gb4[n3 * 16];
            acc.x += w0 * x0.x; acc.y += w0 * x0.y; acc.z += w0 * x0.z; acc.w += w0 * x0.w;
            acc.x += w1 * x1.x; acc.y += w1 * x1.y; acc.z += w1 * x1.z; acc.w += w1 * x1.w;
            acc.x += w2 * x2.x; acc.y += w2 * x2.y; acc.z += w2 * x2.z; acc.w += w2 * x2.w;
            acc.x += w3 * x3.x; acc.y += w3 * x3.y; acc.z += w3 * x3.z; acc.w += w3 * x3.w;
        }
        for (; j < je; ++j) {
            int   n = nbr[i * CAP + j];
            float w = wv[i * CAP + j];
            float4 x = gb4[n * 16];
            acc.x += w * x.x; acc.y += w * x.y; acc.z += w * x.z; acc.w += w * x.w;
        }
        hsPart[q][b][f4] = acc;
    }
    __syncthreads();
    if (t < 128) {
        int b2 = t >> 4, f42 = t & 15;
        float4 s0 = hsPart[0][b2][f42], s1 = hsPart[1][b2][f42];
        float4 s2 = hsPart[2][b2][f42], s3 = hsPart[3][b2][f42];
        hs[b2][f42 * 4 + 0] = s0.x + s1.x + s2.x + s3.x;
        hs[b2][f42 * 4 + 1] = s0.y + s1.y + s2.y + s3.y;
        hs[b2][f42 * 4 + 2] = s0.z + s1.z + s2.z + s3.z;
        hs[b2][f42 * 4 + 3] = s0.w + s1.w + s2.w + s3.w;
    }
    __syncthreads();

    // ---- phase 2: scores + softmax + weighted input sum; wave = batch ----
    int rc = rcnt[i]; if (rc > CAP) rc = CAP;
    int b = t >> 6;                          // 0..7
    int s = t & 63;
    float bias = biasc[comp * NN + i];
    int rounds = (rc + 63) >> 6;             // <= 4
    float sc[4]; int nn4[4];
    float lmax = -3.0e38f;
#pragma unroll
    for (int r = 0; r < 4; ++r) {
        float svv = -3.0e38f; int n = 0;
        if (r < rounds) {
            int k = r * 64 + s;
            if (k < rc) {
                n = rnbr[i * CAP + k];
                const float4* w4 = (const float4*)(w1T + ((size_t)comp * NN + n) * FF);
                float acc = bias;
#pragma unroll
                for (int q = 0; q < 16; ++q) {
                    float4 w = w4[q];
                    acc += hs[b][4*q+0] * w.x + hs[b][4*q+1] * w.y
                         + hs[b][4*q+2] * w.z + hs[b][4*q+3] * w.w;
                }
                svv = acc;
            }
        }
        sc[r] = svv; nn4[r] = n;
        lmax = fmaxf(lmax, svv);
    }
#pragma unroll
    for (int o = 32; o > 0; o >>= 1) lmax = fmaxf(lmax, __shfl_xor(lmax, o));
    float num = 0.0f, den = 0.0f;
#pragma unroll
    for (int r = 0; r < 4; ++r) {
        if (r < rounds) {
            int k = r * 64 + s;
            if (k < rc) {
                float e = expf(sc[r] - lmax);
                den += e;
                num += e * in[((size_t)b * NN + nn4[r]) * 2 + comp];
            }
        }
    }
#pragma unroll
    for (int o = 32; o > 0; o >>= 1) { num += __shfl_xor(num, o); den += __shfl_xor(den, o); }
    if (s == 0) {
        size_t bn = (size_t)b * NN + i;
        pOut[bn * 2 + comp] = num / den + dem[bn * 2 + comp];
    }
}

// ---------------- r,u gates: 512 threads, 2-way j-split, unroll-4 ----------------
__global__ void __launch_bounds__(512)
k_ru(const float* __restrict__ pOut, const float* __restrict__ st,
     const int* __restrict__ cnt, const int* __restrict__ nbrA,
     const float* __restrict__ wAr, const float* __restrict__ wAu,
     const float* __restrict__ br, const float* __restrict__ bu,
     const float* __restrict__ linrW, const float* __restrict__ linrB,
     const float* __restrict__ linuW, const float* __restrict__ linuB,
     float* __restrict__ ubuf, float* __restrict__ rsbuf) {
    int i = blockIdx.x;
    int t = threadIdx.x;                 // 0..511
    int d    = t & 31;
    int b    = (t >> 5) & 7;
    int half = t >> 8;                   // wave-uniform
    __shared__ float LrP[2][8][36], LuP[2][8][36];
    int cc = cnt[i]; if (cc > CAP) cc = CAP;
    int hlen = (cc + 1) >> 1;
    int jb = half * hlen;
    int je = jb + hlen; if (je > cc) je = cc;
    bool dop = (d < 2);
    const float* stb = st + (size_t)b * NN * HH + d;
    const float* pb  = pOut + (size_t)b * NN * 2 + d;
    float ar = 0.f, au = 0.f, arp = 0.f, aup = 0.f;
    int j = jb;
    for (; j + 4 <= je; j += 4) {
        int   n0 = nbrA[i*CAP+j+0], n1 = nbrA[i*CAP+j+1], n2 = nbrA[i*CAP+j+2], n3 = nbrA[i*CAP+j+3];
        float r0 = wAr[i*CAP+j+0], r1 = wAr[i*CAP+j+1], r2 = wAr[i*CAP+j+2], r3 = wAr[i*CAP+j+3];
        float u0 = wAu[i*CAP+j+0], u1 = wAu[i*CAP+j+1], u2 = wAu[i*CAP+j+2], u3 = wAu[i*CAP+j+3];
        float v0 = stb[n0*HH], v1 = stb[n1*HH], v2 = stb[n2*HH], v3 = stb[n3*HH];
        ar += r0*v0 + r1*v1 + r2*v2 + r3*v3;
        au += u0*v0 + u1*v1 + u2*v2 + u3*v3;
        if (dop) {
            float p0 = pb[n0*2], p1 = pb[n1*2], p2 = pb[n2*2], p3 = pb[n3*2];
            arp += r0*p0 + r1*p1 + r2*p2 + r3*p3;
            aup += u0*p0 + u1*p1 + u2*p2 + u3*p3;
        }
    }
    for (; j < je; ++j) {
        int   n  = nbrA[i*CAP+j];
        float r_ = wAr[i*CAP+j];
        float u_ = wAu[i*CAP+j];
        float v  = stb[n*HH];
        ar += r_*v;  au += u_*v;
        if (dop) { float p = pb[n*2]; arp += r_*p; aup += u_*p; }
    }
    LrP[half][b][d + 2] = ar;
    LuP[half][b][d + 2] = au;
    if (dop) { LrP[half][b][d] = arp; LuP[half][b][d] = aup; }
    __syncthreads();
    if (half == 0) {
        float sr = linrB[d], su = linuB[d];
#pragma unroll
        for (int q = 0; q < DIMM; ++q) {
            float lr = LrP[0][b][q] + LrP[1][b][q] + br[q];
            float lu = LuP[0][b][q] + LuP[1][b][q] + bu[q];
            sr += lr * linrW[q * HH + d];
            su += lu * linuW[q * HH + d];
        }
        float r = 1.0f / (1.0f + expf(-sr));
        float u = 1.0f / (1.0f + expf(-su));
        size_t bn = (size_t)b * NN + i;
        rsbuf[bn * HH + d] = r * st[bn * HH + d];
        ubuf [bn * HH + d] = u;
    }
}

// ---------------- c and final H: 512 threads, 2-way j-split, unroll-4 ----------------
__global__ void __launch_bounds__(512)
k_c(const float* __restrict__ g, const float* __restrict__ rsbuf,
    const float* __restrict__ ubuf, const float* __restrict__ st,
    const int* __restrict__ cnt, const int* __restrict__ nbrA,
    const float* __restrict__ wAc, const float* __restrict__ bc,
    const float* __restrict__ lincW, const float* __restrict__ lincB,
    float* __restrict__ Hout) {
    int i = blockIdx.x;
    int t = threadIdx.x;                 // 0..511
    int d    = t & 31;
    int b    = (t >> 5) & 7;
    int half = t >> 8;                   // wave-uniform
    __shared__ float LcP[2][8][68];
    int cc = cnt[i]; if (cc > CAP) cc = CAP;
    int hlen = (cc + 1) >> 1;
    int jb = half * hlen;
    int je = jb + hlen; if (je > cc) je = cc;
    const float* gb  = g + (size_t)b * NN * FF + d;
    const float* rsb = rsbuf + (size_t)b * NN * HH + d;
    float a0 = 0.f, a1 = 0.f;
    int j = jb;
    for (; j + 4 <= je; j += 4) {
        int   n0 = nbrA[i*CAP+j+0], n1 = nbrA[i*CAP+j+1], n2 = nbrA[i*CAP+j+2], n3 = nbrA[i*CAP+j+3];
        float w0 = wAc[i*CAP+j+0], w1 = wAc[i*CAP+j+1], w2 = wAc[i*CAP+j+2], w3 = wAc[i*CAP+j+3];
        float x0 = gb[n0*FF],  x1 = gb[n1*FF],  x2 = gb[n2*FF],  x3 = gb[n3*FF];
        float y0 = rsb[n0*HH], y1 = rsb[n1*HH], y2 = rsb[n2*HH], y3 = rsb[n3*HH];
        a0 += w0*x0 + w1*x1 + w2*x2 + w3*x3;
        a1 += w0*y0 + w1*y1 + w2*y2 + w3*y3;
    }
    for (; j < je; ++j) {
        int   n = nbrA[i*CAP+j];
        float w = wAc[i*CAP+j];
        a0 += w * gb[n*FF];
        a1 += w * rsb[n*HH];
    }
    LcP[half][b][d]      = a0;
    LcP[half][b][d + 32] = a1;
    __syncthreads();
    if (half == 0) {
        float sacc = lincB[d];
#pragma unroll
        for (int q = 0; q < FF; ++q) {
            float lc = LcP[0][b][q] + LcP[1][b][q] + bc[q];
            sacc += lc * lincW[q * HH + d];
        }
        float cv = tanhf(sacc);
        size_t bn = (size_t)b * NN + i;
        float u  = ubuf[bn * HH + d];
        float sv = st[bn * HH + d];
        Hout[bn * HH + d] = u * sv + (1.0f - u) * cv;
    }
}

extern "C" void kernel_launch(void* const* d_in, const int* in_sizes, int n_in,
                              void* d_out, int out_size, void* d_ws, size_t ws_size,
                              hipStream_t stream) {
    const float* input  = (const float*)d_in[0];
    const float* state  = (const float*)d_in[1];
    const float* A      = (const float*)d_in[2];
    const float* Badj   = (const float*)d_in[3];
    const float* w1c    = (const float*)d_in[4];
    const float* w2c    = (const float*)d_in[5];
    const float* biasc  = (const float*)d_in[6];
    const float* convW  = (const float*)d_in[7];
    const float* convb  = (const float*)d_in[8];
    const float* lininW = (const float*)d_in[9];
    const float* lininB = (const float*)d_in[10];
    const float* wr     = (const float*)d_in[11];
    const float* br     = (const float*)d_in[12];
    const float* linrW  = (const float*)d_in[13];
    const float* linrB  = (const float*)d_in[14];
    const float* wu     = (const float*)d_in[15];
    const float* bu     = (const float*)d_in[16];
    const float* linuW  = (const float*)d_in[17];
    const float* linuB  = (const float*)d_in[18];
    const float* wc     = (const float*)d_in[19];
    const float* bc     = (const float*)d_in[20];
    const float* lincW  = (const float*)d_in[21];
    const float* lincB  = (const float*)d_in[22];

    float* ws   = (float*)d_ws;
    float* g    = ws + G_OFF;
    float* dem  = ws + DEM_OFF;
    float* w1T  = ws + W1T_OFF;
    int*   cnt  = (int*)(ws + CNT_OFF);
    int*   nbrA = (int*)(ws + NBRA_OFF);
    int*   rnbrA= (int*)(ws + RNBRA_OFF);
    int*   nbrB = (int*)(ws + NBRB_OFF);
    int*   rnbrB= (int*)(ws + RNBRB_OFF);
    float* wAw2 = ws + WAW2_OFF;
    float* wAr  = ws + WAR_OFF;
    float* wAu  = ws + WAU_OFF;
    float* wAc  = ws + WAC_OFF;
    float* wBw2 = ws + WBW2_OFF;
    float* ubuf = ws + U_OFF;
    float* rsbuf= ws + RS_OFF;

    float* pOut = (float*)d_out;                    // [B,N,2]
    float* Hout = (float*)d_out + BB * NN * 2;      // [B,N,32]

    hipMemsetAsync(cnt, 0, 4 * NN * sizeof(int), stream);

    k_pre<<<BB * NN, 64, 0, stream>>>(input, state, lininW, lininB, convW, convb, g, dem);
    k_trans<<<(2 * NN * FF) / 256, 256, 0, stream>>>(w1c, w1T);
    k_fill<<<(2 * NN) / 4, 256, 0, stream>>>(A, Badj, w2c, wr, wu, wc, cnt,
                                             nbrA, rnbrA, nbrB, rnbrB,
                                             wAw2, wAr, wAu, wAc, wBw2);
    k_attn<<<2 * NN, 512, 0, stream>>>(g, input, dem, w1T, biasc, cnt,
                                       nbrA, wAw2, rnbrA, nbrB, wBw2, rnbrB, pOut);
    k_ru<<<NN, 512, 0, stream>>>(pOut, state, cnt, nbrA, wAr, wAu, br, bu,
                                 linrW, linrB, linuW, linuB, ubuf, rsbuf);
    k_c<<<NN, 512, 0, stream>>>(g, rsbuf, ubuf, state, cnt, nbrA, wAc, bc,
                                lincW, lincB, Hout);
}

// Round 12
// 473.665 us; speedup vs baseline: 2.1986x; 1.0209x over previous
//
#include <hip/hip_runtime.h>
#include <math.h>

#define NN   2048
#define BB   8
#define FF   64
#define HH   32
#define DIMM 34
#define CAP  256

// ---- workspace layout in 4-byte units ----
#define G_OFF      0                          // B*N*64 floats (g = [x,state])
#define DEM_OFF    (G_OFF + BB*NN*FF)         // B*N*2
#define W1T_OFF    (DEM_OFF + BB*NN*2)        // 2*N*64  (w1 transposed)
#define CNT_OFF    (W1T_OFF + 2*NN*FF)        // 4*N ints: ccntA, rcntA, ccntB, rcntB
#define NBRA_OFF   (CNT_OFF + 4*NN)           // N*CAP int  (col lists of A)
#define RNBRA_OFF  (NBRA_OFF + NN*CAP)        // N*CAP int  (row lists of A, sorted)
#define NBRB_OFF   (RNBRA_OFF + NN*CAP)       // N*CAP int
#define RNBRB_OFF  (NBRB_OFF + NN*CAP)        // N*CAP int
#define WAW2_OFF   (RNBRB_OFF + NN*CAP)       // N*CAP f32 (A ⊙ w2c[0], column-packed)
#define WAR_OFF    (WAW2_OFF + NN*CAP)        // A ⊙ wr
#define WAU_OFF    (WAR_OFF + NN*CAP)         // A ⊙ wu
#define WAC_OFF    (WAU_OFF + NN*CAP)         // A ⊙ wc
#define WBW2_OFF   (WAC_OFF + NN*CAP)         // Badj ⊙ w2c[1]
#define U_OFF      (WBW2_OFF + NN*CAP)        // B*N*32 (u)
#define RS_OFF     (U_OFF + BB*NN*HH)         // B*N*32 (r*state)

// ---------------- stage 1: x, g, demand ----------------
__global__ void k_pre(const float* __restrict__ in, const float* __restrict__ st,
                      const float* __restrict__ lininW, const float* __restrict__ lininB,
                      const float* __restrict__ convW, const float* __restrict__ convB,
                      float* __restrict__ g, float* __restrict__ dem) {
    int bn = blockIdx.x;        // b*N+n
    int f  = threadIdx.x;       // 0..63
    float in0 = in[bn * 2 + 0];
    float in1 = in[bn * 2 + 1];
    float gv;
    if (f < HH) gv = in0 * lininW[f] + in1 * lininW[HH + f] + lininB[f];
    else        gv = st[bn * HH + (f - HH)];
    g[bn * FF + f] = gv;
    float p0 = gv * convW[f * 2 + 0];
    float p1 = gv * convW[f * 2 + 1];
    for (int o = 32; o > 0; o >>= 1) { p0 += __shfl_down(p0, o); p1 += __shfl_down(p1, o); }
    if (f == 0) {
        dem[bn * 2 + 0] = tanhf(p0 + convB[0]) * 0.5f;
        dem[bn * 2 + 1] = tanhf(p1 + convB[1]) * 0.5f;
    }
}

// ---------------- transpose w1c[2][64][2048] -> w1T[2][2048][64] ----------------
__global__ void k_trans(const float* __restrict__ w1c, float* __restrict__ w1T) {
    int t = blockIdx.x * 256 + threadIdx.x;     // < 2*64*2048
    int a   = t >> 17;
    int rem = t & 131071;
    int f   = rem >> 11;
    int k   = rem & 2047;
    w1T[a * (NN * FF) + k * FF + f] = w1c[t];
}

// ---------------- build lists: one wave per adjacency row ----------------
__global__ void k_fill(const float* __restrict__ A, const float* __restrict__ Badj,
                       const float* __restrict__ w2c,
                       const float* __restrict__ wr, const float* __restrict__ wu,
                       const float* __restrict__ wc,
                       int* __restrict__ cnt,   // [ccntA, rcntA, ccntB, rcntB]
                       int* __restrict__ nbrA, int* __restrict__ rnbrA,
                       int* __restrict__ nbrB, int* __restrict__ rnbrB,
                       float* __restrict__ wAw2, float* __restrict__ wAr,
                       float* __restrict__ wAu, float* __restrict__ wAc,
                       float* __restrict__ wBw2) {
    int gw   = blockIdx.x * 4 + (threadIdx.x >> 6);   // global wave id, 0..2*NN-1
    int lane = threadIdx.x & 63;
    int comp = (gw >= NN) ? 1 : 0;
    int n    = comp ? gw - NN : gw;
    const float* row = (comp ? Badj : A) + (size_t)n * NN;

    const float4* r4 = (const float4*)row + lane * 8;
    unsigned int msk = 0;
#pragma unroll
    for (int q = 0; q < 8; ++q) {
        float4 v = r4[q];
        msk |= ((unsigned)(v.x != 0.0f)) << (q * 4 + 0);
        msk |= ((unsigned)(v.y != 0.0f)) << (q * 4 + 1);
        msk |= ((unsigned)(v.z != 0.0f)) << (q * 4 + 2);
        msk |= ((unsigned)(v.w != 0.0f)) << (q * 4 + 3);
    }
    int c    = __popc(msk);
    int incl = c;
#pragma unroll
    for (int o = 1; o < 64; o <<= 1) {
        int tv = __shfl_up(incl, o);
        if (lane >= o) incl += tv;
    }
    int slot  = incl - c;
    int total = __shfl(incl, 63);
    if (lane == 0) cnt[(comp ? 3 * NN : NN) + n] = total;

    int* rnbr   = comp ? rnbrB : rnbrA;
    int* nbr    = comp ? nbrB  : nbrA;
    int  colbase= comp ? 2 * NN : 0;
    unsigned int mm = msk;
    while (mm) {
        int p = __ffs(mm) - 1; mm &= mm - 1;
        int m = lane * 32 + p;
        if (slot < CAP) rnbr[n * CAP + slot] = m;
        slot++;
        int cj = atomicAdd(&cnt[colbase + m], 1);
        if (cj < CAP) {
            size_t tI = (size_t)n * NN + m;
            nbr[m * CAP + cj] = n;
            if (!comp) {
                wAw2[m * CAP + cj] = w2c[tI];
                wAr [m * CAP + cj] = wr[tI];
                wAu [m * CAP + cj] = wu[tI];
                wAc [m * CAP + cj] = wc[tI];
            } else {
                wBw2[m * CAP + cj] = w2c[(size_t)NN * NN + tI];
            }
        }
    }
}

// ---------------- fused h-gather + masked softmax + p ----------------
// 1024 threads. Lists staged in LDS. Phase 1: 8-way j-split, float4 gathers.
// Phase 2: 16 waves = (b, round-pair); softmax combined across 2 waves via LDS.
__global__ void __launch_bounds__(1024)
k_attn(const float* __restrict__ g, const float* __restrict__ in,
       const float* __restrict__ dem, const float* __restrict__ w1T,
       const float* __restrict__ biasc, const int* __restrict__ cnt,
       const int* __restrict__ nbrA, const float* __restrict__ wAw2,
       const int* __restrict__ rnbrA,
       const int* __restrict__ nbrB, const float* __restrict__ wBw2,
       const int* __restrict__ rnbrB,
       float* __restrict__ pOut) {
    int blk  = blockIdx.x;                   // 0..2*NN-1
    int comp = (blk >= NN) ? 1 : 0;
    int i    = comp ? blk - NN : blk;
    int t    = threadIdx.x;                  // 0..1023

    const int*   ccnt = cnt + (comp ? 2 * NN : 0);
    const int*   rcnt = cnt + (comp ? 3 * NN : NN);
    const int*   nbrG = comp ? nbrB : nbrA;
    const float* wvG  = comp ? wBw2 : wAw2;
    const int*   rnbG = comp ? rnbrB : rnbrA;

    __shared__ int    cnL[CAP];
    __shared__ float  cwL[CAP];
    __shared__ int    rnL[CAP];
    __shared__ float4 hsPart[8][8][16];      // 16 KB partials
    __shared__ float  hs[8][68];
    __shared__ float  smax[8][2], ssum[8][2], snum[8][2];

    int cc = ccnt[i]; if (cc > CAP) cc = CAP;
    int rc = rcnt[i]; if (rc > CAP) rc = CAP;

    // ---- stage lists into LDS (coalesced) ----
    {
        int k = t & 255, sel = t >> 8;
        if      (sel == 0) cnL[k] = (k < cc) ? nbrG[i * CAP + k] : 0;
        else if (sel == 1) cwL[k] = (k < cc) ? wvG [i * CAP + k] : 0.0f;
        else if (sel == 2) rnL[k] = (k < rc) ? rnbG[i * CAP + k] : 0;
    }
    __syncthreads();

    // ---- phase 1: h[b][f], 8-way j-split ----
    {
        int f4 = t & 15;
        int b  = (t >> 4) & 7;
        int q  = t >> 7;                     // 0..7, uniform per 2 waves
        int qlen = (cc + 7) >> 3;
        int jb = q * qlen;
        int je = jb + qlen; if (je > cc) je = cc;
        const float4* gb4 = (const float4*)g + (size_t)b * NN * 16 + f4;
        float4 acc = make_float4(0.f, 0.f, 0.f, 0.f);
        int j = jb;
        for (; j + 4 <= je; j += 4) {
            int   n0 = cnL[j + 0], n1 = cnL[j + 1], n2 = cnL[j + 2], n3 = cnL[j + 3];
            float w0 = cwL[j + 0], w1 = cwL[j + 1], w2 = cwL[j + 2], w3 = cwL[j + 3];
            float4 x0 = gb4[n0 * 16], x1 = gb4[n1 * 16];
            float4 x2 = gb4[n2 * 16], x3 = gb4[n3 * 16];
            acc.x += w0 * x0.x; acc.y += w0 * x0.y; acc.z += w0 * x0.z; acc.w += w0 * x0.w;
            acc.x += w1 * x1.x; acc.y += w1 * x1.y; acc.z += w1 * x1.z; acc.w += w1 * x1.w;
            acc.x += w2 * x2.x; acc.y += w2 * x2.y; acc.z += w2 * x2.z; acc.w += w2 * x2.w;
            acc.x += w3 * x3.x; acc.y += w3 * x3.y; acc.z += w3 * x3.z; acc.w += w3 * x3.w;
        }
        for (; j < je; ++j) {
            int   n = cnL[j];
            float w = cwL[j];
            float4 x = gb4[n * 16];
            acc.x += w * x.x; acc.y += w * x.y; acc.z += w * x.z; acc.w += w * x.w;
        }
        hsPart[q][b][f4] = acc;
    }
    __syncthreads();
    if (t < 128) {
        int b2 = t >> 4, f42 = t & 15;
        float4 s = hsPart[0][b2][f42];
#pragma unroll
        for (int q = 1; q < 8; ++q) {
            float4 p = hsPart[q][b2][f42];
            s.x += p.x; s.y += p.y; s.z += p.z; s.w += p.w;
        }
        hs[b2][f42 * 4 + 0] = s.x;
        hs[b2][f42 * 4 + 1] = s.y;
        hs[b2][f42 * 4 + 2] = s.z;
        hs[b2][f42 * 4 + 3] = s.w;
    }
    __syncthreads();

    // ---- phase 2: wave = (b, rr); k = rr*64+s and (rr+2)*64+s ----
    int s  = t & 63;
    int wI = t >> 6;                         // 0..15
    int b  = wI & 7;
    int rr = wI >> 3;                        // 0..1
    float bias = biasc[comp * NN + i];
    int k0 = rr * 64 + s;
    int k1 = (rr + 2) * 64 + s;
    float sc0 = -3.0e38f, sc1 = -3.0e38f;
    int n0 = 0, n1 = 0;
    if (k0 < rc) {
        n0 = rnL[k0];
        const float4* w4 = (const float4*)(w1T + ((size_t)comp * NN + n0) * FF);
        float a = bias;
#pragma unroll
        for (int q = 0; q < 16; ++q) {
            float4 w = w4[q];
            a += hs[b][4*q+0]*w.x + hs[b][4*q+1]*w.y + hs[b][4*q+2]*w.z + hs[b][4*q+3]*w.w;
        }
        sc0 = a;
    }
    if (k1 < rc) {
        n1 = rnL[k1];
        const float4* w4 = (const float4*)(w1T + ((size_t)comp * NN + n1) * FF);
        float a = bias;
#pragma unroll
        for (int q = 0; q < 16; ++q) {
            float4 w = w4[q];
            a += hs[b][4*q+0]*w.x + hs[b][4*q+1]*w.y + hs[b][4*q+2]*w.z + hs[b][4*q+3]*w.w;
        }
        sc1 = a;
    }
    float lmax = fmaxf(sc0, sc1);
#pragma unroll
    for (int o = 32; o > 0; o >>= 1) lmax = fmaxf(lmax, __shfl_xor(lmax, o));
    if (s == 0) smax[b][rr] = lmax;
    __syncthreads();
    float gmax = fmaxf(smax[b][0], smax[b][1]);
    float num = 0.0f, den = 0.0f;
    if (k0 < rc) {
        float e = expf(sc0 - gmax);
        den += e;
        num += e * in[((size_t)b * NN + n0) * 2 + comp];
    }
    if (k1 < rc) {
        float e = expf(sc1 - gmax);
        den += e;
        num += e * in[((size_t)b * NN + n1) * 2 + comp];
    }
#pragma unroll
    for (int o = 32; o > 0; o >>= 1) { num += __shfl_xor(num, o); den += __shfl_xor(den, o); }
    if (s == 0) { ssum[b][rr] = den; snum[b][rr] = num; }
    __syncthreads();
    if (rr == 0 && s == 0) {
        float td = ssum[b][0] + ssum[b][1];
        float tn = snum[b][0] + snum[b][1];
        size_t bn = (size_t)b * NN + i;
        pOut[bn * 2 + comp] = tn / td + dem[bn * 2 + comp];
    }
}

// ---------------- r,u gates: 1024 threads, LDS lists, 4-way j-split ----------------
__global__ void __launch_bounds__(1024)
k_ru(const float* __restrict__ pOut, const float* __restrict__ st,
     const int* __restrict__ cnt, const int* __restrict__ nbrA,
     const float* __restrict__ wAr, const float* __restrict__ wAu,
     const float* __restrict__ br, const float* __restrict__ bu,
     const float* __restrict__ linrW, const float* __restrict__ linrB,
     const float* __restrict__ linuW, const float* __restrict__ linuB,
     float* __restrict__ ubuf, float* __restrict__ rsbuf) {
    int i = blockIdx.x;
    int t = threadIdx.x;                 // 0..1023
    int d = t & 31;
    int b = (t >> 5) & 7;
    int q = t >> 8;                      // 0..3, wave-uniform
    __shared__ int   cnL[CAP];
    __shared__ float cwrL[CAP], cwuL[CAP];
    __shared__ float LrP[4][8][36], LuP[4][8][36];
    int cc = cnt[i]; if (cc > CAP) cc = CAP;
    {
        int k = t & 255, sel = t >> 8;
        if      (sel == 0) cnL [k] = (k < cc) ? nbrA[i * CAP + k] : 0;
        else if (sel == 1) cwrL[k] = (k < cc) ? wAr [i * CAP + k] : 0.0f;
        else if (sel == 2) cwuL[k] = (k < cc) ? wAu [i * CAP + k] : 0.0f;
    }
    __syncthreads();
    int qlen = (cc + 3) >> 2;
    int jb = q * qlen;
    int je = jb + qlen; if (je > cc) je = cc;
    bool dop = (d < 2);
    const float* stb = st + (size_t)b * NN * HH + d;
    const float* pb  = pOut + (size_t)b * NN * 2 + d;
    float ar = 0.f, au = 0.f, arp = 0.f, aup = 0.f;
    int j = jb;
    for (; j + 4 <= je; j += 4) {
        int   n0 = cnL[j+0], n1 = cnL[j+1], n2 = cnL[j+2], n3 = cnL[j+3];
        float r0 = cwrL[j+0], r1 = cwrL[j+1], r2 = cwrL[j+2], r3 = cwrL[j+3];
        float u0 = cwuL[j+0], u1 = cwuL[j+1], u2 = cwuL[j+2], u3 = cwuL[j+3];
        float v0 = stb[n0*HH], v1 = stb[n1*HH], v2 = stb[n2*HH], v3 = stb[n3*HH];
        ar += r0*v0 + r1*v1 + r2*v2 + r3*v3;
        au += u0*v0 + u1*v1 + u2*v2 + u3*v3;
        if (dop) {
            float p0 = pb[n0*2], p1 = pb[n1*2], p2 = pb[n2*2], p3 = pb[n3*2];
            arp += r0*p0 + r1*p1 + r2*p2 + r3*p3;
            aup += u0*p0 + u1*p1 + u2*p2 + u3*p3;
        }
    }
    for (; j < je; ++j) {
        int   n  = cnL[j];
        float r_ = cwrL[j];
        float u_ = cwuL[j];
        float v  = stb[n*HH];
        ar += r_*v;  au += u_*v;
        if (dop) { float p = pb[n*2]; arp += r_*p; aup += u_*p; }
    }
    LrP[q][b][d + 2] = ar;
    LuP[q][b][d + 2] = au;
    if (dop) { LrP[q][b][d] = arp; LuP[q][b][d] = aup; }
    __syncthreads();
    if (q == 0) {
        float sr = linrB[d], su = linuB[d];
#pragma unroll
        for (int k = 0; k < DIMM; ++k) {
            float lr = LrP[0][b][k] + LrP[1][b][k] + LrP[2][b][k] + LrP[3][b][k] + br[k];
            float lu = LuP[0][b][k] + LuP[1][b][k] + LuP[2][b][k] + LuP[3][b][k] + bu[k];
            sr += lr * linrW[k * HH + d];
            su += lu * linuW[k * HH + d];
        }
        float r = 1.0f / (1.0f + expf(-sr));
        float u = 1.0f / (1.0f + expf(-su));
        size_t bn = (size_t)b * NN + i;
        rsbuf[bn * HH + d] = r * st[bn * HH + d];
        ubuf [bn * HH + d] = u;
    }
}

// ---------------- c and final H: 1024 threads, LDS lists, 4-way j-split ----------------
__global__ void __launch_bounds__(1024)
k_c(const float* __restrict__ g, const float* __restrict__ rsbuf,
    const float* __restrict__ ubuf, const float* __restrict__ st,
    const int* __restrict__ cnt, const int* __restrict__ nbrA,
    const float* __restrict__ wAc, const float* __restrict__ bc,
    const float* __restrict__ lincW, const float* __restrict__ lincB,
    float* __restrict__ Hout) {
    int i = blockIdx.x;
    int t = threadIdx.x;                 // 0..1023
    int d = t & 31;
    int b = (t >> 5) & 7;
    int q = t >> 8;                      // 0..3, wave-uniform
    __shared__ int   cnL[CAP];
    __shared__ float cwcL[CAP];
    __shared__ float LcP[4][8][68];
    int cc = cnt[i]; if (cc > CAP) cc = CAP;
    {
        int k = t & 255, sel = t >> 8;
        if      (sel == 0) cnL [k] = (k < cc) ? nbrA[i * CAP + k] : 0;
        else if (sel == 1) cwcL[k] = (k < cc) ? wAc [i * CAP + k] : 0.0f;
    }
    __syncthreads();
    int qlen = (cc + 3) >> 2;
    int jb = q * qlen;
    int je = jb + qlen; if (je > cc) je = cc;
    const float* gb  = g + (size_t)b * NN * FF + d;
    const float* rsb = rsbuf + (size_t)b * NN * HH + d;
    float a0 = 0.f, a1 = 0.f;
    int j = jb;
    for (; j + 4 <= je; j += 4) {
        int   n0 = cnL[j+0], n1 = cnL[j+1], n2 = cnL[j+2], n3 = cnL[j+3];
        float w0 = cwcL[j+0], w1 = cwcL[j+1], w2 = cwcL[j+2], w3 = cwcL[j+3];
        float x0 = gb[n0*FF],  x1 = gb[n1*FF],  x2 = gb[n2*FF],  x3 = gb[n3*FF];
        float y0 = rsb[n0*HH], y1 = rsb[n1*HH], y2 = rsb[n2*HH], y3 = rsb[n3*HH];
        a0 += w0*x0 + w1*x1 + w2*x2 + w3*x3;
        a1 += w0*y0 + w1*y1 + w2*y2 + w3*y3;
    }
    for (; j < je; ++j) {
        int   n = cnL[j];
        float w = cwcL[j];
        a0 += w * gb[n*FF];
        a1 += w * rsb[n*HH];
    }
    LcP[q][b][d]      = a0;
    LcP[q][b][d + 32] = a1;
    __syncthreads();
    if (q == 0) {
        float sacc = lincB[d];
#pragma unroll
        for (int k = 0; k < FF; ++k) {
            float lc = LcP[0][b][k] + LcP[1][b][k] + LcP[2][b][k] + LcP[3][b][k] + bc[k];
            sacc += lc * lincW[k * HH + d];
        }
        float cv = tanhf(sacc);
        size_t bn = (size_t)b * NN + i;
        float u  = ubuf[bn * HH + d];
        float sv = st[bn * HH + d];
        Hout[bn * HH + d] = u * sv + (1.0f - u) * cv;
    }
}

extern "C" void kernel_launch(void* const* d_in, const int* in_sizes, int n_in,
                              void* d_out, int out_size, void* d_ws, size_t ws_size,
                              hipStream_t stream) {
    const float* input  = (const float*)d_in[0];
    const float* state  = (const float*)d_in[1];
    const float* A      = (const float*)d_in[2];
    const float* Badj   = (const float*)d_in[3];
    const float* w1c    = (const float*)d_in[4];
    const float* w2c    = (const float*)d_in[5];
    const float* biasc  = (const float*)d_in[6];
    const float* convW  = (const float*)d_in[7];
    const float* convb  = (const float*)d_in[8];
    const float* lininW = (const float*)d_in[9];
    const float* lininB = (const float*)d_in[10];
    const float* wr     = (const float*)d_in[11];
    const float* br     = (const float*)d_in[12];
    const float* linrW  = (const float*)d_in[13];
    const float* linrB  = (const float*)d_in[14];
    const float* wu     = (const float*)d_in[15];
    const float* bu     = (const float*)d_in[16];
    const float* linuW  = (const float*)d_in[17];
    const float* linuB  = (const float*)d_in[18];
    const float* wc     = (const float*)d_in[19];
    const float* bc     = (const float*)d_in[20];
    const float* lincW  = (const float*)d_in[21];
    const float* lincB  = (const float*)d_in[22];

    float* ws   = (float*)d_ws;
    float* g    = ws + G_OFF;
    float* dem  = ws + DEM_OFF;
    float* w1T  = ws + W1T_OFF;
    int*   cnt  = (int*)(ws + CNT_OFF);
    int*   nbrA = (int*)(ws + NBRA_OFF);
    int*   rnbrA= (int*)(ws + RNBRA_OFF);
    int*   nbrB = (int*)(ws + NBRB_OFF);
    int*   rnbrB= (int*)(ws + RNBRB_OFF);
    float* wAw2 = ws + WAW2_OFF;
    float* wAr  = ws + WAR_OFF;
    float* wAu  = ws + WAU_OFF;
    float* wAc  = ws + WAC_OFF;
    float* wBw2 = ws + WBW2_OFF;
    float* ubuf = ws + U_OFF;
    float* rsbuf= ws + RS_OFF;

    float* pOut = (float*)d_out;                    // [B,N,2]
    float* Hout = (float*)d_out + BB * NN * 2;      // [B,N,32]

    hipMemsetAsync(cnt, 0, 4 * NN * sizeof(int), stream);

    k_pre<<<BB * NN, 64, 0, stream>>>(input, state, lininW, lininB, convW, convb, g, dem);
    k_trans<<<(2 * NN * FF) / 256, 256, 0, stream>>>(w1c, w1T);
    k_fill<<<(2 * NN) / 4, 256, 0, stream>>>(A, Badj, w2c, wr, wu, wc, cnt,
                                             nbrA, rnbrA, nbrB, rnbrB,
                                             wAw2, wAr, wAu, wAc, wBw2);
    k_attn<<<2 * NN, 1024, 0, stream>>>(g, input, dem, w1T, biasc, cnt,
                                        nbrA, wAw2, rnbrA, nbrB, wBw2, rnbrB, pOut);
    k_ru<<<NN, 1024, 0, stream>>>(pOut, state, cnt, nbrA, wAr, wAu, br, bu,
                                  linrW, linrB, linuW, linuB, ubuf, rsbuf);
    k_c<<<NN, 1024, 0, stream>>>(g, rsbuf, ubuf, state, cnt, nbrA, wAc, bc,
                                 lincW, lincB, Hout);
}